// Round 11
// baseline (272.282 us; speedup 1.0000x reference)
//
#include <hip/hip_runtime.h>
#include <hip/hip_bf16.h>
#include <math.h>

// Problem constants (fixed shapes from setup_inputs)
#define B_   16
#define F_   2048
#define N_   64
#define K_   1024   // F/2
#define YP   2056   // padded LDS row stride (ushorts)

typedef short bf16x8 __attribute__((ext_vector_type(8)));  // 8 bf16 = 4 VGPR
typedef float v4f    __attribute__((ext_vector_type(4)));  // MFMA C/D frag

__device__ __forceinline__ float wave_sum(float v) {
#pragma unroll
  for (int off = 32; off > 0; off >>= 1) v += __shfl_down(v, off, 64);
  return v;
}
__device__ __forceinline__ float wave_max(float v) {
#pragma unroll
  for (int off = 32; off > 0; off >>= 1) v = fmaxf(v, __shfl_down(v, off, 64));
  return v;
}

// fp32 -> bf16 bits, round-to-nearest-even (finite inputs only)
__device__ __forceinline__ unsigned f2bf(float x) {
  const unsigned u = __float_as_uint(x);
  return (u + 0x7FFFu + ((u >> 16) & 1u)) >> 16;
}
__device__ __forceinline__ float bf2f(unsigned us) {
  return __uint_as_float(us << 16);
}
// 16-bit total-order inverse: ord -> bf16 bits
__device__ __forceinline__ unsigned ord2u16(unsigned T) {
  return (T & 0x8000u) ? (T ^ 0x8000u) : (T ^ 0xFFFFu);
}
// packed pair of ord16 keys from a dword of 2 bf16 values
__device__ __forceinline__ unsigned ordpair(unsigned wd) {
  return wd ^ (0x80008000u | (((wd & 0x80008000u) >> 15) * 0x7FFFu));
}

// K0: per-(b,n) feature stats: sum(x), sum(x^2) for X and M via atomics.
// 1024 blocks (4 blocks/CU) — round-10's 256-block grid ran 1 block/CU.
__global__ __launch_bounds__(256) void stats_kernel(
    const float* __restrict__ X, const float* __restrict__ M,
    float* __restrict__ gstats) {
  const int tid = threadIdx.x;
  const int b = blockIdx.x >> 6;
  const int f0 = (blockIdx.x & 63) * 32;
  const int fi = tid >> 6, n = tid & 63;
  float sx = 0.f, sxx = 0.f, sm = 0.f, smm = 0.f;
#pragma unroll
  for (int j = 0; j < 8; ++j) {
    const int f = f0 + fi + 4 * j;
    const size_t gi = ((size_t)b * F_ + f) * N_ + n;
    const float x = X[gi];
    const float m = M[gi];
    sx += x; sxx += x * x; sm += m; smm += m * m;
  }
  float* g = gstats + ((size_t)b * N_ + n) * 4;
  atomicAdd(&g[0], sx);
  atomicAdd(&g[1], sxx);
  atomicAdd(&g[2], sm);
  atomicAdd(&g[3], smm);
}

// K1: center + L2-normalize per (b,n); write bf16 in the ORIGINAL [b][f][n]
// layout (n=k contiguous) — exactly the MFMA fragment order. 1024 blocks.
__global__ __launch_bounds__(256) void normbf_kernel(
    const float* __restrict__ X, const float* __restrict__ M,
    const float* __restrict__ gstats,
    short* __restrict__ Xb16, short* __restrict__ Mb16) {
  const int tid = threadIdx.x;
  const int b = blockIdx.x >> 6;
  const int f0 = (blockIdx.x & 63) * 32;
  const int n = tid & 63;
  const float* g = gstats + ((size_t)b * N_ + n) * 4;
  const float sx = g[0], sxx = g[1], sm = g[2], smm = g[3];
  const float mux = sx * (1.f / F_), mum = sm * (1.f / F_);
  const float rx = 1.f / (sqrtf(fmaxf(sxx - (float)F_ * mux * mux, 0.f)) + 1e-10f);
  const float rm = 1.f / (sqrtf(fmaxf(smm - (float)F_ * mum * mum, 0.f)) + 1e-10f);
#pragma unroll
  for (int jj = 0; jj < 8; ++jj) {
    const int f = f0 + (tid >> 6) + 4 * jj;
    const size_t gi = ((size_t)b * F_ + f) * N_ + n;
    Xb16[gi] = (short)f2bf((X[gi] - mux) * rx);
    Mb16[gi] = (short)f2bf((M[gi] - mum) * rm);
  }
}

// K2: block = 512 threads (8 waves), 16 rows of YX[b]. Each wave GEMMs a
// 256-col slice (16 MFMA tiles), then selects its 2 rows with a FUSED
// dual-row straight-line pipeline: fixed 2-pass floating radix (16-bit keys
// guarantee pass-1 shift <=8 -> pass-2 shift 0; finished rows idempotent via
// lo=T,R=0), both rows sharing one histogram with packed 16-bit counters
// (row0 +=1, row1 +=0x10000; counts <=2048, no carry). One packed
// suffix-scan serves both rows; all per-row chains are independent ILP.
// Round-10 evidence: selection was latency-bound (VALUBusy fell 48->39%
// with no time gain) at 4 waves/SIMD.
__global__ __launch_bounds__(512)
__attribute__((amdgpu_waves_per_eu(4, 4)))
void rows_kernel(
    const short* __restrict__ Xb16, const short* __restrict__ Mb16,
    float* __restrict__ C) {
  __shared__ unsigned short yxu[16 * YP];   // 65,792 B
  __shared__ unsigned histS[8 * 256];       // 8 KB: per-wave packed dual hist

  const int tid = threadIdx.x;
  const int w = tid >> 6, lane = tid & 63;
  const int nl = lane & 15, q = lane >> 4;
  const int b = blockIdx.x >> 7;            // 128 row-blocks per batch
  const int f0 = (blockIdx.x & 127) * 16;
  const int g0 = 256 * w;

  const short* __restrict__ Xb = Xb16 + (size_t)b * F_ * N_;
  const short* __restrict__ Mb = Mb16 + (size_t)b * F_ * N_;

  // A-frags (rows f0..f0+15): A[m=nl][k=32*s+8*q+j]
  const short* Ax = Xb + (size_t)(f0 + nl) * N_ + 8 * q;
  const short* Am = Mb + (size_t)(f0 + nl) * N_ + 8 * q;
  const bf16x8 ax0 = *(const bf16x8*)(Ax);
  const bf16x8 ax1 = *(const bf16x8*)(Ax + 32);
  const bf16x8 am0 = *(const bf16x8*)(Am);
  const bf16x8 am1 = *(const bf16x8*)(Am + 32);

  v4f acc[16];
#pragma unroll
  for (int t = 0; t < 16; ++t) acc[t] = (v4f)(0.f);

#pragma unroll
  for (int t = 0; t < 16; ++t) {
    // B[k][n=nl]: YX[f][g] = sum_k X[k][f]M[k][g] + M[k][f]X[k][g]
    const short* Bm = Mb + (size_t)(g0 + 16 * t + nl) * N_ + 8 * q;
    const short* Bx = Xb + (size_t)(g0 + 16 * t + nl) * N_ + 8 * q;
    const bf16x8 bm0 = *(const bf16x8*)(Bm);
    const bf16x8 bm1 = *(const bf16x8*)(Bm + 32);
    const bf16x8 bx0 = *(const bf16x8*)(Bx);
    const bf16x8 bx1 = *(const bf16x8*)(Bx + 32);
    acc[t] = __builtin_amdgcn_mfma_f32_16x16x32_bf16(ax0, bm0, acc[t], 0, 0, 0);
    acc[t] = __builtin_amdgcn_mfma_f32_16x16x32_bf16(ax1, bm1, acc[t], 0, 0, 0);
    acc[t] = __builtin_amdgcn_mfma_f32_16x16x32_bf16(am0, bx0, acc[t], 0, 0, 0);
    acc[t] = __builtin_amdgcn_mfma_f32_16x16x32_bf16(am1, bx1, acc[t], 0, 0, 0);
  }

  // C-frag (col=lane&15, row=q*4+r, verified m89/m91) -> LDS bf16 keys
#pragma unroll
  for (int t = 0; t < 16; ++t) {
    const int col = g0 + 16 * t + nl;
#pragma unroll
    for (int r = 0; r < 4; ++r)
      yxu[(4 * q + r) * YP + col] = (unsigned short)f2bf(acc[t][r]);
  }
  __syncthreads();

  // ---- fused dual-row selection: rows 2w, 2w+1 ----
  unsigned* wh = &histS[w << 8];   // 256 words; low16 = row0, high16 = row1
  const int frow0 = f0 + 2 * w, frow1 = f0 + 2 * w + 1;
  const uint4* rp0 = (const uint4*)(yxu + (2 * w) * YP);
  const uint4* rp1 = (const uint4*)(yxu + (2 * w + 1) * YP);

  // single LDS read pass per row: pack 2x ord16 keys per dword + ranges
  unsigned pk0[16], pk1[16];
  unsigned kmin0 = 0xFFFFFFFFu, kmax0 = 0u, kmin1 = 0xFFFFFFFFu, kmax1 = 0u;
#pragma unroll
  for (int j = 0; j < 4; ++j) {
    const uint4 t0 = rp0[lane + 64 * j];
    const uint4 t1 = rp1[lane + 64 * j];
    const unsigned w0[4] = {t0.x, t0.y, t0.z, t0.w};
    const unsigned w1[4] = {t1.x, t1.y, t1.z, t1.w};
#pragma unroll
    for (int c = 0; c < 4; ++c) {
      const unsigned oa = ordpair(w0[c]);
      pk0[4 * j + c] = oa;
      kmin0 = min(kmin0, min(oa & 0xFFFFu, oa >> 16));
      kmax0 = max(kmax0, max(oa & 0xFFFFu, oa >> 16));
      const unsigned ob = ordpair(w1[c]);
      pk1[4 * j + c] = ob;
      kmin1 = min(kmin1, min(ob & 0xFFFFu, ob >> 16));
      kmax1 = max(kmax1, max(ob & 0xFFFFu, ob >> 16));
    }
  }
#pragma unroll
  for (int off = 32; off > 0; off >>= 1) {
    kmin0 = min(kmin0, (unsigned)__shfl_down((int)kmin0, off, 64));
    kmax0 = max(kmax0, (unsigned)__shfl_down((int)kmax0, off, 64));
    kmin1 = min(kmin1, (unsigned)__shfl_down((int)kmin1, off, 64));
    kmax1 = max(kmax1, (unsigned)__shfl_down((int)kmax1, off, 64));
  }
  kmin0 = (unsigned)__shfl((int)kmin0, 0, 64);
  kmax0 = (unsigned)__shfl((int)kmax0, 0, 64);
  kmin1 = (unsigned)__shfl((int)kmin1, 0, 64);
  kmax1 = (unsigned)__shfl((int)kmax1, 0, 64);

  unsigned lo0 = kmin0, R0 = kmax0 - kmin0, krem0 = K_, T0 = 0, tie0 = 0;
  unsigned lo1 = kmin1, R1 = kmax1 - kmin1, krem1 = K_, T1 = 0, tie1 = 0;

#pragma unroll
  for (int pass = 0; pass < 2; ++pass) {
    const int pos0 = 31 - __builtin_clz(R0 | 1u);
    const int sh0 = (pos0 > 7) ? (pos0 - 7) : 0;
    const int pos1 = 31 - __builtin_clz(R1 | 1u);
    const int sh1 = (pos1 > 7) ? (pos1 - 7) : 0;
#pragma unroll
    for (int i = 0; i < 4; ++i) wh[lane + 64 * i] = 0u;
    __builtin_amdgcn_wave_barrier();
#pragma unroll
    for (int c = 0; c < 16; ++c) {
      const unsigned oa = pk0[c];
      const unsigned a0 = (oa & 0xFFFFu) - lo0, a1 = (oa >> 16) - lo0;
      if (a0 <= R0) atomicAdd(&wh[a0 >> sh0], 1u);
      if (a1 <= R0) atomicAdd(&wh[a1 >> sh0], 1u);
      const unsigned ob = pk1[c];
      const unsigned b0 = (ob & 0xFFFFu) - lo1, b1 = (ob >> 16) - lo1;
      if (b0 <= R1) atomicAdd(&wh[b0 >> sh1], 0x10000u);
      if (b1 <= R1) atomicAdd(&wh[b1 >> sh1], 0x10000u);
    }
    __builtin_amdgcn_wave_barrier();
    unsigned h[4];
#pragma unroll
    for (int i = 0; i < 4; ++i) h[i] = wh[4 * lane + i];
    const unsigned s3 = h[3], s2 = h[2] + s3, s1 = h[1] + s2, s0 = h[0] + s1;
    unsigned tot = s0;                        // packed suffix scan (both rows)
#pragma unroll
    for (int off = 1; off < 64; off <<= 1) {
      const unsigned v = __shfl_down(tot, off, 64);
      if (lane + off < 64) tot += v;
    }
    const unsigned above = tot - s0;          // packed
    const unsigned S[4] = {above + s0, above + s1, above + s2, above + s3};
    unsigned p0 = 0, p1 = 0;
    bool fb0 = false, fb1 = false;
#pragma unroll
    for (int i = 0; i < 4; ++i) {
      const unsigned Sl = S[i] & 0xFFFFu, hl = h[i] & 0xFFFFu;
      const unsigned Spl = Sl - hl;
      if (Sl >= krem0 && Spl < krem0) {
        p0 = ((unsigned)(4 * lane + i) << 16) | Spl; fb0 = true;
      }
      const unsigned Sh = S[i] >> 16, hh = h[i] >> 16;
      const unsigned Sph = Sh - hh;
      if (Sh >= krem1 && Sph < krem1) {
        p1 = ((unsigned)(4 * lane + i) << 16) | Sph; fb1 = true;
      }
    }
    const int wi0 = __ffsll(__ballot(fb0)) - 1;
    const int wi1 = __ffsll(__ballot(fb1)) - 1;
    p0 = (unsigned)__shfl((int)p0, wi0, 64);
    p1 = (unsigned)__shfl((int)p1, wi1, 64);
    const unsigned D0 = p0 >> 16, D1 = p1 >> 16;
    krem0 -= (p0 & 0xFFFFu);
    krem1 -= (p1 & 0xFFFFu);
    if (sh0 == 0) { T0 = lo0 + D0; tie0 = krem0; lo0 = T0; R0 = 0; }
    else          { lo0 += (D0 << sh0); R0 = (1u << sh0) - 1u; }
    if (sh1 == 0) { T1 = lo1 + D1; tie1 = krem1; lo1 = T1; R1 = 0; }
    else          { lo1 += (D1 << sh1); R1 = (1u << sh1) - 1u; }
  }

  // final pass (register keys): sums over key > T, tie counts per group.
  // No exp max-shift: |yx| <= 2 (unit columns) so exp can't overflow.
  float vs0 = 0.f, ws0 = 0.f, vs1 = 0.f, ws1 = 0.f;
  unsigned cnt0[4], cnt1[4];
#pragma unroll
  for (int j = 0; j < 4; ++j) {
    cnt0[j] = 0; cnt1[j] = 0;
#pragma unroll
    for (int c = 0; c < 4; ++c) {
      const unsigned oa = pk0[4 * j + c];
      const unsigned aa[2] = {oa & 0xFFFFu, oa >> 16};
      const unsigned ob = pk1[4 * j + c];
      const unsigned bb[2] = {ob & 0xFFFFu, ob >> 16};
#pragma unroll
      for (int i = 0; i < 2; ++i) {
        const int g = 512 * j + 8 * lane + 2 * c + i;
        if (aa[i] > T0) {
          const float pv = __expf(bf2f(ord2u16(aa[i])));
          vs0 += pv; ws0 += pv * fabsf((float)(g - frow0));
        } else if (aa[i] == T0) cnt0[j]++;
        if (bb[i] > T1) {
          const float pv = __expf(bf2f(ord2u16(bb[i])));
          vs1 += pv; ws1 += pv * fabsf((float)(g - frow1));
        } else if (bb[i] == T1) cnt1[j]++;
      }
    }
  }
  const float pt0 = __expf(bf2f(ord2u16(T0)));
  const float pt1 = __expf(bf2f(ord2u16(T1)));

  // index-ordered tie selection: 16-bit-field scans, both rows interleaved
  unsigned pA0 = cnt0[0] | (cnt0[1] << 16), pB0 = cnt0[2] | (cnt0[3] << 16);
  unsigned pA1 = cnt1[0] | (cnt1[1] << 16), pB1 = cnt1[2] | (cnt1[3] << 16);
  unsigned iA0 = pA0, iB0 = pB0, iA1 = pA1, iB1 = pB1;
#pragma unroll
  for (int off = 1; off < 64; off <<= 1) {
    const unsigned vA0 = __shfl_up(iA0, off, 64);
    const unsigned vB0 = __shfl_up(iB0, off, 64);
    const unsigned vA1 = __shfl_up(iA1, off, 64);
    const unsigned vB1 = __shfl_up(iB1, off, 64);
    if (lane >= off) { iA0 += vA0; iB0 += vB0; iA1 += vA1; iB1 += vB1; }
  }
  const unsigned eA0 = iA0 - pA0, eB0 = iB0 - pB0;
  const unsigned eA1 = iA1 - pA1, eB1 = iB1 - pB1;
  const unsigned tA0 = (unsigned)__shfl((int)iA0, 63, 64);
  const unsigned tB0 = (unsigned)__shfl((int)iB0, 63, 64);
  const unsigned tA1 = (unsigned)__shfl((int)iA1, 63, 64);
  const unsigned tB1 = (unsigned)__shfl((int)iB1, 63, 64);
  unsigned G0[4], G1[4];
  G0[0] = 0;
  G0[1] = G0[0] + (tA0 & 0xFFFFu);
  G0[2] = G0[1] + (tA0 >> 16);
  G0[3] = G0[2] + (tB0 & 0xFFFFu);
  G1[0] = 0;
  G1[1] = G1[0] + (tA1 & 0xFFFFu);
  G1[2] = G1[1] + (tA1 >> 16);
  G1[3] = G1[2] + (tB1 & 0xFFFFu);
#pragma unroll
  for (int j = 0; j < 4; ++j) {
    if (cnt0[j]) {
      const unsigned off = (j < 2) ? ((eA0 >> (16 * j)) & 0xFFFFu)
                                   : ((eB0 >> (16 * (j - 2))) & 0xFFFFu);
      unsigned cc = 0;
#pragma unroll
      for (int c = 0; c < 4; ++c) {
        const unsigned o = pk0[4 * j + c];
        const unsigned oo[2] = {o & 0xFFFFu, o >> 16};
#pragma unroll
        for (int i = 0; i < 2; ++i) {
          if (oo[i] == T0) {
            if (G0[j] + off + cc < tie0) {
              const int g = 512 * j + 8 * lane + 2 * c + i;
              vs0 += pt0; ws0 += pt0 * fabsf((float)(g - frow0));
            }
            cc++;
          }
        }
      }
    }
    if (cnt1[j]) {
      const unsigned off = (j < 2) ? ((eA1 >> (16 * j)) & 0xFFFFu)
                                   : ((eB1 >> (16 * (j - 2))) & 0xFFFFu);
      unsigned cc = 0;
#pragma unroll
      for (int c = 0; c < 4; ++c) {
        const unsigned o = pk1[4 * j + c];
        const unsigned oo[2] = {o & 0xFFFFu, o >> 16};
#pragma unroll
        for (int i = 0; i < 2; ++i) {
          if (oo[i] == T1) {
            if (G1[j] + off + cc < tie1) {
              const int g = 512 * j + 8 * lane + 2 * c + i;
              vs1 += pt1; ws1 += pt1 * fabsf((float)(g - frow1));
            }
            cc++;
          }
        }
      }
    }
  }

  vs0 = wave_sum(vs0); ws0 = wave_sum(ws0);
  vs1 = wave_sum(vs1); ws1 = wave_sum(ws1);
  if (lane == 0) {
    C[(size_t)b * F_ + frow0] = (ws0 / vs0) * (1.f / (float)K_);
    C[(size_t)b * F_ + frow1] = (ws1 / vs1) * (1.f / (float)K_);
  }
}

// K3: cmin = min(C); out = mean(exp(-C + cmin - 1e-6)); hedged write.
__global__ __launch_bounds__(1024) void final_kernel(
    const float* __restrict__ C, unsigned* __restrict__ out) {
  __shared__ float red[16];
  const int tid = threadIdx.x;
  const int wave = tid >> 6, lane = tid & 63;
  float v[32];
  float mn = 3.4e38f;
#pragma unroll
  for (int i = 0; i < 32; ++i) {
    v[i] = C[tid + 1024 * i];
    mn = fminf(mn, v[i]);
  }
  mn = -wave_max(-mn);
  if (lane == 0) red[wave] = mn;
  __syncthreads();
  float cmin = red[0];
  for (int w = 1; w < 16; ++w) cmin = fminf(cmin, red[w]);
  __syncthreads();
  float s = 0.f;
#pragma unroll
  for (int i = 0; i < 32; ++i) s += expf(cmin - v[i] - 1e-6f);
  s = wave_sum(s);
  if (lane == 0) red[wave] = s;
  __syncthreads();
  if (tid == 0) {
    float tot = 0.f;
    for (int w = 0; w < 16; ++w) tot += red[w];
    const float res = tot * (1.f / 32768.f);
    const __hip_bfloat16 hb = __float2bfloat16(res);
    const unsigned short u = *(const unsigned short*)&hb;
    out[0] = ((unsigned)u << 16) | (unsigned)u;
  }
}

extern "C" void kernel_launch(void* const* d_in, const int* in_sizes, int n_in,
                              void* d_out, int out_size, void* d_ws, size_t ws_size,
                              hipStream_t stream) {
  const float* X = (const float*)d_in[0];
  const float* M = (const float*)d_in[1];
  short* Xb16 = (short*)d_ws;                          // 4 MB (16*2048*64 bf16)
  short* Mb16 = Xb16 + (size_t)B_ * F_ * N_;           // 4 MB
  float* C = (float*)(Mb16 + (size_t)B_ * F_ * N_);    // 128 KB
  float* gstats = C + (size_t)B_ * F_;                 // 16 KB

  hipMemsetAsync(gstats, 0, (size_t)B_ * N_ * 4 * sizeof(float), stream);
  stats_kernel<<<dim3(B_ * 64), dim3(256), 0, stream>>>(X, M, gstats);
  normbf_kernel<<<dim3(B_ * 64), dim3(256), 0, stream>>>(X, M, gstats, Xb16, Mb16);
  rows_kernel<<<dim3(B_ * (F_ / 16)), dim3(512), 0, stream>>>(Xb16, Mb16, C);
  final_kernel<<<dim3(1), dim3(1024), 0, stream>>>(C, (unsigned*)d_out);
}

// Round 12
// 230.834 us; speedup vs baseline: 1.1796x; 1.1796x over previous
//
#include <hip/hip_runtime.h>
#include <hip/hip_bf16.h>
#include <math.h>

// Problem constants (fixed shapes from setup_inputs)
#define B_   16
#define F_   2048
#define N_   64
#define K_   1024   // F/2
#define YP   2056   // padded LDS row stride (ushorts)

typedef short bf16x8 __attribute__((ext_vector_type(8)));  // 8 bf16 = 4 VGPR
typedef float v4f    __attribute__((ext_vector_type(4)));  // MFMA C/D frag

__device__ __forceinline__ float wave_sum(float v) {
#pragma unroll
  for (int off = 32; off > 0; off >>= 1) v += __shfl_down(v, off, 64);
  return v;
}
__device__ __forceinline__ float wave_max(float v) {
#pragma unroll
  for (int off = 32; off > 0; off >>= 1) v = fmaxf(v, __shfl_down(v, off, 64));
  return v;
}

// fp32 -> bf16 bits, round-to-nearest-even (finite inputs only)
__device__ __forceinline__ unsigned f2bf(float x) {
  const unsigned u = __float_as_uint(x);
  return (u + 0x7FFFu + ((u >> 16) & 1u)) >> 16;
}
__device__ __forceinline__ float bf2f(unsigned us) {
  return __uint_as_float(us << 16);
}
// 16-bit total-order inverse: ord -> bf16 bits
__device__ __forceinline__ unsigned ord2u16(unsigned T) {
  return (T & 0x8000u) ? (T ^ 0x8000u) : (T ^ 0xFFFFu);
}
// packed pair of ord16 keys from a dword of 2 bf16 values
__device__ __forceinline__ unsigned ordpair(unsigned wd) {
  return wd ^ (0x80008000u | (((wd & 0x80008000u) >> 15) * 0x7FFFu));
}

// K0: per-(b,n) feature stats, ATOMIC-FREE: each block LDS-reduces its
// 128-f chunk and writes its own slot P[b][n][word][fb] (fb-contiguous so
// normbf reduces 16 slots with contiguous loads). No memset needed.
// (Round-11 lesson: growing the stats grid 4x with per-thread atomics
// quadrupled contention and cost ~35 us.)
__global__ __launch_bounds__(256) void stats_kernel(
    const float* __restrict__ X, const float* __restrict__ M,
    float* __restrict__ P) {
  __shared__ float red[4][N_][4];   // [fi][n][word], 4 KB
  const int tid = threadIdx.x;
  const int b = blockIdx.x >> 4;
  const int fb = blockIdx.x & 15;
  const int f0 = fb * 128;
  const int fi = tid >> 6, n = tid & 63;
  float sx = 0.f, sxx = 0.f, sm = 0.f, smm = 0.f;
#pragma unroll 4
  for (int j = 0; j < 32; ++j) {
    const int f = f0 + fi + 4 * j;
    const size_t gi = ((size_t)b * F_ + f) * N_ + n;
    const float x = X[gi];
    const float m = M[gi];
    sx += x; sxx += x * x; sm += m; smm += m * m;
  }
  red[fi][n][0] = sx; red[fi][n][1] = sxx;
  red[fi][n][2] = sm; red[fi][n][3] = smm;
  __syncthreads();
  // 256 threads: (n, word) each sums the 4 fi partials, writes own slot
  const int wn = tid & 63, word = tid >> 6;
  const float s = red[0][wn][word] + red[1][wn][word] +
                  red[2][wn][word] + red[3][wn][word];
  P[(((size_t)b * N_ + wn) * 4 + word) * 16 + fb] = s;
}

// K1: center + L2-normalize per (b,n); write bf16 in the ORIGINAL [b][f][n]
// layout (n=k contiguous) — exactly the MFMA fragment order.
__global__ __launch_bounds__(256) void normbf_kernel(
    const float* __restrict__ X, const float* __restrict__ M,
    const float* __restrict__ P,
    short* __restrict__ Xb16, short* __restrict__ Mb16) {
  const int tid = threadIdx.x;
  const int b = blockIdx.x >> 4;
  const int f0 = (blockIdx.x & 15) * 128;
  const int n = tid & 63;
  const float* base = P + (((size_t)b * N_ + n) * 4) * 16;
  float acc4[4];
#pragma unroll
  for (int wj = 0; wj < 4; ++wj) {
    float s = 0.f;
#pragma unroll
    for (int i = 0; i < 16; ++i) s += base[16 * wj + i];
    acc4[wj] = s;
  }
  const float sx = acc4[0], sxx = acc4[1], sm = acc4[2], smm = acc4[3];
  const float mux = sx * (1.f / F_), mum = sm * (1.f / F_);
  const float rx = 1.f / (sqrtf(fmaxf(sxx - (float)F_ * mux * mux, 0.f)) + 1e-10f);
  const float rm = 1.f / (sqrtf(fmaxf(smm - (float)F_ * mum * mum, 0.f)) + 1e-10f);
#pragma unroll 4
  for (int jj = 0; jj < 32; ++jj) {
    const int f = f0 + (tid >> 6) + 4 * jj;
    const size_t gi = ((size_t)b * F_ + f) * N_ + n;
    Xb16[gi] = (short)f2bf((X[gi] - mux) * rx);
    Mb16[gi] = (short)f2bf((M[gi] - mum) * rm);
  }
}

// K2 (round-10 verified best: 165 us): block = 512 threads (8 waves),
// 16 rows of YX[b]. Each wave GEMMs a 256-col slice (16 MFMA tiles), then
// selects 2 full rows. Selection reads the row from LDS ONCE, packing 2x
// ord16 keys per VGPR; radix/final/tie passes run register-resident. No exp
// max-shift: |yx| <= 2 so exp can't overflow and the shift cancels in ws/vs.
__global__ __launch_bounds__(512)
__attribute__((amdgpu_waves_per_eu(4, 4)))
void rows_kernel(
    const short* __restrict__ Xb16, const short* __restrict__ Mb16,
    float* __restrict__ C) {
  __shared__ unsigned short yxu[16 * YP];   // 65,792 B
  __shared__ unsigned histS[8 * 256];       // 8 KB per-wave histograms

  const int tid = threadIdx.x;
  const int w = tid >> 6, lane = tid & 63;
  const int nl = lane & 15, q = lane >> 4;
  const int b = blockIdx.x >> 7;            // 128 row-blocks per batch
  const int f0 = (blockIdx.x & 127) * 16;
  const int g0 = 256 * w;

  const short* __restrict__ Xb = Xb16 + (size_t)b * F_ * N_;
  const short* __restrict__ Mb = Mb16 + (size_t)b * F_ * N_;

  // A-frags (rows f0..f0+15): A[m=nl][k=32*s+8*q+j]
  const short* Ax = Xb + (size_t)(f0 + nl) * N_ + 8 * q;
  const short* Am = Mb + (size_t)(f0 + nl) * N_ + 8 * q;
  const bf16x8 ax0 = *(const bf16x8*)(Ax);
  const bf16x8 ax1 = *(const bf16x8*)(Ax + 32);
  const bf16x8 am0 = *(const bf16x8*)(Am);
  const bf16x8 am1 = *(const bf16x8*)(Am + 32);

  v4f acc[16];
#pragma unroll
  for (int t = 0; t < 16; ++t) acc[t] = (v4f)(0.f);

#pragma unroll
  for (int t = 0; t < 16; ++t) {
    // B[k][n=nl]: YX[f][g] = sum_k X[k][f]M[k][g] + M[k][f]X[k][g]
    const short* Bm = Mb + (size_t)(g0 + 16 * t + nl) * N_ + 8 * q;
    const short* Bx = Xb + (size_t)(g0 + 16 * t + nl) * N_ + 8 * q;
    const bf16x8 bm0 = *(const bf16x8*)(Bm);
    const bf16x8 bm1 = *(const bf16x8*)(Bm + 32);
    const bf16x8 bx0 = *(const bf16x8*)(Bx);
    const bf16x8 bx1 = *(const bf16x8*)(Bx + 32);
    acc[t] = __builtin_amdgcn_mfma_f32_16x16x32_bf16(ax0, bm0, acc[t], 0, 0, 0);
    acc[t] = __builtin_amdgcn_mfma_f32_16x16x32_bf16(ax1, bm1, acc[t], 0, 0, 0);
    acc[t] = __builtin_amdgcn_mfma_f32_16x16x32_bf16(am0, bx0, acc[t], 0, 0, 0);
    acc[t] = __builtin_amdgcn_mfma_f32_16x16x32_bf16(am1, bx1, acc[t], 0, 0, 0);
  }

  // C-frag (col=lane&15, row=q*4+r, verified m89/m91) -> LDS bf16 keys
#pragma unroll
  for (int t = 0; t < 16; ++t) {
    const int col = g0 + 16 * t + nl;
#pragma unroll
    for (int r = 0; r < 4; ++r)
      yxu[(4 * q + r) * YP + col] = (unsigned short)f2bf(acc[t][r]);
  }
  __syncthreads();

  // ---- per-wave selection: rows 2w, 2w+1; 32 keys/lane (register-cached) --
  unsigned* wh = &histS[w << 8];
#pragma unroll 1
  for (int r4 = 0; r4 < 2; ++r4) {
    const int row = 2 * w + r4;
    const int frow = f0 + row;
    const uint4* rp = (const uint4*)(yxu + row * YP);  // 16B-aligned

    // single LDS pass: pack 2x16-bit total-order keys per dword + range
    unsigned pk[16];
    unsigned kmin = 0xFFFFFFFFu, kmax = 0u;
#pragma unroll
    for (int j = 0; j < 4; ++j) {
      const uint4 tt = rp[lane + 64 * j];
      const unsigned wds[4] = {tt.x, tt.y, tt.z, tt.w};
#pragma unroll
      for (int c = 0; c < 4; ++c) {
        const unsigned o = ordpair(wds[c]);
        pk[4 * j + c] = o;   // packed ord16 pair; uint order == float order
        const unsigned o0 = o & 0xFFFFu, o1 = o >> 16;
        kmin = min(kmin, min(o0, o1));
        kmax = max(kmax, max(o0, o1));
      }
    }
#pragma unroll
    for (int off = 32; off > 0; off >>= 1) {
      kmin = min(kmin, (unsigned)__shfl_down((int)kmin, off, 64));
      kmax = max(kmax, (unsigned)__shfl_down((int)kmax, off, 64));
    }
    kmin = (unsigned)__shfl((int)kmin, 0, 64);
    kmax = (unsigned)__shfl((int)kmax, 0, 64);

    // exact 1024-th largest: floating radix on 16-bit ord keys (<=2 passes)
    unsigned lo = kmin, R = kmax - kmin, krem = K_;
    unsigned T, tie_need;
    if (R == 0) {
      T = lo; tie_need = krem;
    } else {
      for (;;) {
        const int pos = 31 - __builtin_clz(R);
        const int sh = (pos > 7) ? (pos - 7) : 0;
#pragma unroll
        for (int i = 0; i < 4; ++i) wh[lane + 64 * i] = 0u;
        __builtin_amdgcn_wave_barrier();
#pragma unroll
        for (int c = 0; c < 16; ++c) {
          const unsigned o = pk[c];
          const unsigned d0 = (o & 0xFFFFu) - lo;
          const unsigned d1 = (o >> 16) - lo;
          if (d0 <= R) atomicAdd(&wh[d0 >> sh], 1u);
          if (d1 <= R) atomicAdd(&wh[d1 >> sh], 1u);
        }
        __builtin_amdgcn_wave_barrier();
        unsigned h[4];
#pragma unroll
        for (int i = 0; i < 4; ++i) h[i] = wh[4 * lane + i];
        unsigned s3 = h[3], s2 = h[2] + s3, s1 = h[1] + s2, s0 = h[0] + s1;
        unsigned tot = s0;
#pragma unroll
        for (int off = 1; off < 64; off <<= 1) {
          const unsigned v = __shfl_down(tot, off, 64);
          if (lane + off < 64) tot += v;
        }
        const unsigned above = tot - s0;  // count with bucket >= 4*(lane+1)
        const unsigned S[4] = {above + s0, above + s1, above + s2, above + s3};
        unsigned packed = 0;
        bool found = false;
#pragma unroll
        for (int i = 0; i < 4; ++i) {
          const unsigned Sip1 = S[i] - h[i];
          if (S[i] >= krem && Sip1 < krem) {
            packed = ((unsigned)(4 * lane + i) << 16) | Sip1;
            found = true;
          }
        }
        const unsigned long long bm = __ballot(found);
        const int winner = __ffsll(bm) - 1;
        packed = (unsigned)__shfl((int)packed, winner, 64);
        const unsigned D = packed >> 16;
        krem -= (packed & 0xFFFFu);
        if (sh == 0) { T = lo + D; tie_need = krem; break; }
        lo += (D << sh);
        R = (1u << sh) - 1u;
      }
    }

    // final pass (register keys): sums over key > T, tie counts per group
    float vs = 0.f, ws = 0.f;
    unsigned cnt[4];
#pragma unroll
    for (int j = 0; j < 4; ++j) {
      cnt[j] = 0;
#pragma unroll
      for (int c = 0; c < 4; ++c) {
        const unsigned o = pk[4 * j + c];
        const unsigned oo[2] = {o & 0xFFFFu, o >> 16};
#pragma unroll
        for (int i = 0; i < 2; ++i) {
          const int g = 512 * j + 8 * lane + 2 * c + i;
          if (oo[i] > T) {
            const float pv = __expf(bf2f(ord2u16(oo[i])));
            vs += pv; ws += pv * fabsf((float)(g - frow));
          } else if (oo[i] == T) cnt[j]++;
        }
      }
    }
    const float ptie = __expf(bf2f(ord2u16(T)));

    // index-ordered tie selection: 16-bit-field scans (2 fields/word, <=512)
    unsigned pA = cnt[0] | (cnt[1] << 16), pB = cnt[2] | (cnt[3] << 16);
    unsigned iA = pA, iB = pB;
#pragma unroll
    for (int off = 1; off < 64; off <<= 1) {
      const unsigned vA = __shfl_up(iA, off, 64);
      const unsigned vB = __shfl_up(iB, off, 64);
      if (lane >= off) { iA += vA; iB += vB; }
    }
    const unsigned eA = iA - pA, eB = iB - pB;
    const unsigned tA = (unsigned)__shfl((int)iA, 63, 64);
    const unsigned tB = (unsigned)__shfl((int)iB, 63, 64);
    unsigned G[4];
    G[0] = 0;
    G[1] = G[0] + (tA & 0xFFFFu);
    G[2] = G[1] + (tA >> 16);
    G[3] = G[2] + (tB & 0xFFFFu);
#pragma unroll
    for (int j = 0; j < 4; ++j) {
      if (cnt[j]) {
        const unsigned off = (j < 2) ? ((eA >> (16 * j)) & 0xFFFFu)
                                     : ((eB >> (16 * (j - 2))) & 0xFFFFu);
        unsigned cc = 0;
#pragma unroll
        for (int c = 0; c < 4; ++c) {
          const unsigned o = pk[4 * j + c];
          const unsigned oo[2] = {o & 0xFFFFu, o >> 16};
#pragma unroll
          for (int i = 0; i < 2; ++i) {
            if (oo[i] == T) {
              if (G[j] + off + cc < tie_need) {
                const int g = 512 * j + 8 * lane + 2 * c + i;
                vs += ptie; ws += ptie * fabsf((float)(g - frow));
              }
              cc++;
            }
          }
        }
      }
    }

    vs = wave_sum(vs); ws = wave_sum(ws);
    if (lane == 0)
      C[(size_t)b * F_ + frow] = (ws / vs) * (1.f / (float)K_);
  }
}

// K3: cmin = min(C); out = mean(exp(-C + cmin - 1e-6)); hedged write.
__global__ __launch_bounds__(1024) void final_kernel(
    const float* __restrict__ C, unsigned* __restrict__ out) {
  __shared__ float red[16];
  const int tid = threadIdx.x;
  const int wave = tid >> 6, lane = tid & 63;
  float v[32];
  float mn = 3.4e38f;
#pragma unroll
  for (int i = 0; i < 32; ++i) {
    v[i] = C[tid + 1024 * i];
    mn = fminf(mn, v[i]);
  }
  mn = -wave_max(-mn);
  if (lane == 0) red[wave] = mn;
  __syncthreads();
  float cmin = red[0];
  for (int w = 1; w < 16; ++w) cmin = fminf(cmin, red[w]);
  __syncthreads();
  float s = 0.f;
#pragma unroll
  for (int i = 0; i < 32; ++i) s += expf(cmin - v[i] - 1e-6f);
  s = wave_sum(s);
  if (lane == 0) red[wave] = s;
  __syncthreads();
  if (tid == 0) {
    float tot = 0.f;
    for (int w = 0; w < 16; ++w) tot += red[w];
    const float res = tot * (1.f / 32768.f);
    const __hip_bfloat16 hb = __float2bfloat16(res);
    const unsigned short u = *(const unsigned short*)&hb;
    out[0] = ((unsigned)u << 16) | (unsigned)u;
  }
}

extern "C" void kernel_launch(void* const* d_in, const int* in_sizes, int n_in,
                              void* d_out, int out_size, void* d_ws, size_t ws_size,
                              hipStream_t stream) {
  const float* X = (const float*)d_in[0];
  const float* M = (const float*)d_in[1];
  short* Xb16 = (short*)d_ws;                          // 4 MB (16*2048*64 bf16)
  short* Mb16 = Xb16 + (size_t)B_ * F_ * N_;           // 4 MB
  float* C = (float*)(Mb16 + (size_t)B_ * F_ * N_);    // 128 KB
  float* P = C + (size_t)B_ * F_;                      // 256 KB partial stats

  stats_kernel<<<dim3(B_ * 16), dim3(256), 0, stream>>>(X, M, P);
  normbf_kernel<<<dim3(B_ * 16), dim3(256), 0, stream>>>(X, M, P, Xb16, Mb16);
  rows_kernel<<<dim3(B_ * (F_ / 16)), dim3(512), 0, stream>>>(Xb16, Mb16, C);
  final_kernel<<<dim3(1), dim3(1024), 0, stream>>>(C, (unsigned*)d_out);
}